// Round 18
// baseline (266.705 us; speedup 1.0000x reference)
//
#include <hip/hip_runtime.h>
#include <hip/hip_bf16.h>
#include <hip/hip_fp16.h>

typedef unsigned int u32;
typedef unsigned short u16;
typedef unsigned char u8;
typedef _Float16 f16;

static constexpr int HWn = 65536;

typedef __attribute__((ext_vector_type(8))) f16 f16x8;
typedef __attribute__((ext_vector_type(2))) f16 f16x2;
typedef __attribute__((ext_vector_type(4))) float f32x4;
typedef __attribute__((ext_vector_type(2))) float f32x2;

__device__ __forceinline__ float h2f(u16 u) {
    union { u16 s; f16 h; } z; z.s = u; return (float)z.h;
}
__device__ __forceinline__ u16 f2h(float f) {
    union { u16 s; f16 h; } z; z.h = (f16)f; return z.s;
}
__device__ __forceinline__ u32 pack2h(float a, float b) {
    union { u32 i; f16 h[2]; } z; z.h[0] = (f16)a; z.h[1] = (f16)b; return z.i;
}
__device__ __forceinline__ float hlo(u32 u) {
    union { u32 i; f16 h[2]; } z; z.i = u; return (float)z.h[0];
}
__device__ __forceinline__ float hhi(u32 u) {
    union { u32 i; f16 h[2]; } z; z.i = u; return (float)z.h[1];
}
__device__ __forceinline__ float sq2h(u32 a) {
    const float l = hlo(a), h = hhi(a);
    return fmaf(l, l, h * h);
}

#if defined(__has_builtin)
#if __has_builtin(__builtin_amdgcn_fdot2)
#define HAS_FDOT2 1
#endif
#endif
__device__ __forceinline__ float fdot2a(u32 a, u32 b, float c) {
#ifdef HAS_FDOT2
    union { u32 i; f16x2 h; } A, B; A.i = a; B.i = b;
    return __builtin_amdgcn_fdot2(A.h, B.h, c, false);
#else
    return fmaf(hlo(a), hlo(b), fmaf(hhi(a), hhi(b), c));
#endif
}

// Swizzled LDS offset (u16 units) for transposed X tile: [px 0..127][ic 0..95]
__device__ __forceinline__ int xoff(int px, int icb) {
    return px * 128 + (((icb ^ (px & 7) ^ ((px >> 3) & 7))) << 3);
}

// Convert conv1x1 weights to f16, layout [row 0..287][ic 0..95]
__global__ __launch_bounds__(256) void k_prep_w(
    const float* __restrict__ wq, const float* __restrict__ wkv,
    u16* __restrict__ wf)
{
    const int i = blockIdx.x * 256 + threadIdx.x;
    if (i >= 288 * 96) return;
    const int row = i / 96, ic = i % 96;
    const float w = (row < 96) ? wq[row * 96 + ic] : wkv[(row - 96) * 96 + ic];
    wf[i] = f2h(w);
}

// K1: conv1x1 via f16 MFMA (R17-passing version, unchanged). 4-subtile deep
// pipeline, 2x32KB LDS dbuf. q,k stored fp8-e4m3, v stored f16.
__global__ __launch_bounds__(256, 2) void k_conv_mfma(
    const float* __restrict__ ff, const float* __restrict__ x,
    const u16* __restrict__ wf,
    u8* __restrict__ qk8, u16* __restrict__ v16)
{
    const int b = blockIdx.z, sec = blockIdx.y;
    const int pxg = blockIdx.x * 512;
    const int tid = threadIdx.x;

    __shared__ __align__(16) u16 xs[2][16384];  // 2 x 32 KB, f16 bits

    const float* src = (sec == 0 ? ff : x) + (size_t)b * 96 * HWn;
    const int icq = (tid >> 4) * 2;
    const int pxs = (tid & 15) * 8;
    const int lane = tid & 63;
    const int wv = tid >> 6;
    const int oc0 = (wv >> 1) * 48;
    const int pxw = (wv & 1) * 64;
    const int lr = lane & 15, lg = lane >> 4;

    float4 L0[12], L1[12];

    auto issue = [&](int px0, float4* L) {
        #pragma unroll
        for (int p = 0; p < 3; ++p) {
            const float* rp0 = src + (size_t)(p * 32 + icq) * HWn + px0 + pxs;
            const float* rp1 = rp0 + HWn;
            L[p * 4 + 0] = *reinterpret_cast<const float4*>(rp0);
            L[p * 4 + 1] = *reinterpret_cast<const float4*>(rp0 + 4);
            L[p * 4 + 2] = *reinterpret_cast<const float4*>(rp1);
            L[p * 4 + 3] = *reinterpret_cast<const float4*>(rp1 + 4);
        }
    };
    auto stage = [&](const float4* L, u16* xsb) {
        #pragma unroll
        for (int p = 0; p < 3; ++p) {
            const int ic = p * 32 + icq;
            const int icb = ic >> 3, icl = ic & 7;
            const float e0[8] = {L[p*4+0].x, L[p*4+0].y, L[p*4+0].z, L[p*4+0].w,
                                 L[p*4+1].x, L[p*4+1].y, L[p*4+1].z, L[p*4+1].w};
            const float e1[8] = {L[p*4+2].x, L[p*4+2].y, L[p*4+2].z, L[p*4+2].w,
                                 L[p*4+3].x, L[p*4+3].y, L[p*4+3].z, L[p*4+3].w};
            #pragma unroll
            for (int j = 0; j < 8; ++j) {
                const int o = xoff(pxs + j, icb) + icl;   // even
                *reinterpret_cast<u32*>(&xsb[o]) = pack2h(e0[j], e1[j]);
            }
        }
    };
    auto compute = [&](const u16* xsb, int x0) {
        const int npass = (sec == 0) ? 1 : 2;
        #pragma unroll 1
        for (int kvs = 0; kvs < npass; ++kvs) {
            const u16* wh = wf + ((sec == 0) ? 0 : (96 + kvs * 96)) * 96;
            const bool isv = (sec == 1) && (kvs == 1);
            f32x4 acc[4][3];                     // [px-frag n][oc-frag m]
            #pragma unroll
            for (int n = 0; n < 4; ++n)
                #pragma unroll
                for (int m = 0; m < 3; ++m)
                    acc[n][m] = (f32x4){0.f, 0.f, 0.f, 0.f};

            #pragma unroll 1
            for (int kt = 0; kt < 3; ++kt) {
                const int kb = kt * 32;
                f16x8 XA[4];
                #pragma unroll
                for (int n = 0; n < 4; ++n)
                    XA[n] = *(const f16x8*)(xsb + xoff(pxw + n * 16 + lr, (kb >> 3) + lg));
                f16x8 WB[3];
                #pragma unroll
                for (int m = 0; m < 3; ++m)
                    WB[m] = *(const f16x8*)(wh + (oc0 + m * 16 + lr) * 96 + kb + lg * 8);
                #pragma unroll
                for (int n = 0; n < 4; ++n)
                    #pragma unroll
                    for (int m = 0; m < 3; ++m)
                        acc[n][m] = __builtin_amdgcn_mfma_f32_16x16x32_f16(XA[n], WB[m], acc[n][m], 0, 0, 0);
            }

            // lane owns px = x0 + pxw + n*16 + lg*4 (+0..3), oc = oc0 + m*16 + lr
            if (!isv) {
                u8* dst8 = qk8 + ((size_t)b * 192 + (sec == 0 ? 0 : 96)) * (size_t)HWn;
                #pragma unroll
                for (int n = 0; n < 4; ++n) {
                    #pragma unroll
                    for (int m = 0; m < 3; ++m) {
                        const int oc = oc0 + m * 16 + lr;
                        u32 pk = (u32)__builtin_amdgcn_cvt_pk_fp8_f32(acc[n][m][0], acc[n][m][1], 0, false);
                        pk = (u32)__builtin_amdgcn_cvt_pk_fp8_f32(acc[n][m][2], acc[n][m][3], (int)pk, true);
                        *reinterpret_cast<u32*>(dst8 + (size_t)oc * HWn + x0 + pxw + n * 16 + lg * 4) = pk;
                    }
                }
            } else {
                u16* dstv = v16 + (size_t)b * 96 * HWn;
                #pragma unroll
                for (int n = 0; n < 4; ++n) {
                    #pragma unroll
                    for (int m = 0; m < 3; ++m) {
                        const int oc = oc0 + m * 16 + lr;
                        ushort4 sv;
                        sv.x = f2h(acc[n][m][0]); sv.y = f2h(acc[n][m][1]);
                        sv.z = f2h(acc[n][m][2]); sv.w = f2h(acc[n][m][3]);
                        *reinterpret_cast<ushort4*>(dstv + (size_t)oc * HWn + x0 + pxw + n * 16 + lg * 4) = sv;
                    }
                }
            }
        }
    };

    issue(pxg, L0);
    stage(L0, xs[0]);
    issue(pxg + 128, L1);
    __syncthreads();
    compute(xs[0], pxg);
    stage(L1, xs[1]);
    issue(pxg + 256, L0);
    __syncthreads();
    compute(xs[1], pxg + 128);
    stage(L0, xs[0]);
    issue(pxg + 384, L1);
    __syncthreads();
    compute(xs[0], pxg + 256);
    stage(L1, xs[1]);
    __syncthreads();
    compute(xs[1], pxg + 384);
}

// K2: depthwise 3x3 for q,k (fp8 planes 0..191) + ssq + S via MFMA.
// 16 px/thread (uint4 loads), 3 plane-iters, halved load/shuffle counts.
// 128-px half-row tiles, 512 thr, 52 KB LDS, 1-deep prefetch.
__global__ __launch_bounds__(512) void k_dw_qk(
    const u8* __restrict__ qk8,
    const float* __restrict__ wqdw, const float* __restrict__ wkvdw,
    float* __restrict__ ssq, float* __restrict__ Sg)
{
    const int bid = blockIdx.x;                  // 0..2047
    const int wg = (bid & 7) * 256 + (bid >> 3); // XCD: contiguous y span per XCD
    const int b = wg >> 9;
    const int rem = wg & 511;
    const int y = rem >> 1;
    const int tx = (rem & 1) * 128;
    const int tid = threadIdx.x;
    const int lane = tid & 63;
    const int pq = tid >> 3;                     // 0..63 plane-within-iter
    const int chunk = tid & 7;                   // 8 chunks x 16 px
    const int x0l = chunk * 16;
    const int xg = tx + x0l;

    const bool vr0 = (y > 0), vr2 = (y < 255);
    const bool le = (chunk == 0) && (xg > 0);
    const bool re = (chunk == 7) && (xg + 16 < 256);

    __shared__ __align__(16) u16 qs[96][136];
    __shared__ __align__(16) u16 ks[96][136];

    auto addr = [&](int it, const u8*& r0, const float*& wp, int& c, int& seg) {
        const int p = it * 64 + pq;              // 0..191 == plane index
        r0 = qk8 + ((size_t)(b * 192 + p)) * HWn + (y - 1) * 256 + xg;
        if (p < 96) { c = p;      wp = wqdw  + p * 9;        seg = 0; }
        else        { c = p - 96; wp = wkvdw + (p - 96) * 9; seg = 1; }
    };
    // edge bytes staged so left sits at byte3, right at byte0 (const cvt sel)
    auto issue = [&](const u8* r0, uint4* m, u32* el, u32* er) {
        const uint4 z = make_uint4(0u, 0u, 0u, 0u);
        const u8* r1 = r0 + 256;
        const u8* r2 = r1 + 256;
        m[0] = vr0 ? *reinterpret_cast<const uint4*>(r0) : z;
        m[1] = *reinterpret_cast<const uint4*>(r1);
        m[2] = vr2 ? *reinterpret_cast<const uint4*>(r2) : z;
        el[0] = (le && vr0) ? ((u32)r0[-1] << 24) : 0u;  er[0] = (re && vr0) ? (u32)r0[16] : 0u;
        el[1] = le ? ((u32)r1[-1] << 24) : 0u;           er[1] = re ? (u32)r1[16] : 0u;
        el[2] = (le && vr2) ? ((u32)r2[-1] << 24) : 0u;  er[2] = (re && vr2) ? (u32)r2[16] : 0u;
    };

    const u8* srcC; const float* wpC; int cC, segC;
    addr(0, srcC, wpC, cC, segC);
    uint4 mcur[3]; u32 elc[3], erc[3];
    issue(srcC, mcur, elc, erc);

    #pragma unroll 1
    for (int it = 0; it < 3; ++it) {
        const u8* srcN; const float* wpN; int cN, segN;
        uint4 mnx[3]; u32 eln[3], ern[3];
        if (it < 2) {
            addr(it + 1, srcN, wpN, cN, segN);
            issue(srcN, mnx, eln, ern);
        }

        float a[16];
        #pragma unroll
        for (int j = 0; j < 16; ++j) a[j] = 0.f;

        #pragma unroll
        for (int r = 0; r < 3; ++r) {
            const uint4 u = mcur[r];
            const u32 ln = (u32)__shfl((int)u.w, (lane - 1) & 63);
            const u32 rn = (u32)__shfl((int)u.x, (lane + 1) & 63);
            const u32 lsel = (chunk == 0) ? elc[r] : ln;   // want byte3
            const u32 rsel = (chunk == 7) ? erc[r] : rn;   // want byte0
            const f32x2 lcv = __builtin_amdgcn_cvt_pk_f32_fp8((int)lsel, true);
            const f32x2 rcv = __builtin_amdgcn_cvt_pk_f32_fp8((int)rsel, false);
            const f32x2 c0 = __builtin_amdgcn_cvt_pk_f32_fp8((int)u.x, false);
            const f32x2 c1 = __builtin_amdgcn_cvt_pk_f32_fp8((int)u.x, true);
            const f32x2 c2 = __builtin_amdgcn_cvt_pk_f32_fp8((int)u.y, false);
            const f32x2 c3 = __builtin_amdgcn_cvt_pk_f32_fp8((int)u.y, true);
            const f32x2 c4 = __builtin_amdgcn_cvt_pk_f32_fp8((int)u.z, false);
            const f32x2 c5 = __builtin_amdgcn_cvt_pk_f32_fp8((int)u.z, true);
            const f32x2 c6 = __builtin_amdgcn_cvt_pk_f32_fp8((int)u.w, false);
            const f32x2 c7 = __builtin_amdgcn_cvt_pk_f32_fp8((int)u.w, true);
            const float v[18] = {
                lcv[1],
                c0[0], c0[1], c1[0], c1[1], c2[0], c2[1], c3[0], c3[1],
                c4[0], c4[1], c5[0], c5[1], c6[0], c6[1], c7[0], c7[1],
                rcv[0]
            };
            const float w0 = wpC[r * 3 + 0], w1 = wpC[r * 3 + 1], w2 = wpC[r * 3 + 2];
            #pragma unroll
            for (int j = 0; j < 16; ++j)
                a[j] = fmaf(w0, v[j], fmaf(w1, v[j + 1], fmaf(w2, v[j + 2], a[j])));
        }

        u16* drow = (segC == 0) ? &qs[cC][x0l] : &ks[cC][x0l];
        const uint4 o0 = make_uint4(pack2h(a[0], a[1]), pack2h(a[2], a[3]),
                                    pack2h(a[4], a[5]), pack2h(a[6], a[7]));
        const uint4 o1 = make_uint4(pack2h(a[8], a[9]), pack2h(a[10], a[11]),
                                    pack2h(a[12], a[13]), pack2h(a[14], a[15]));
        *reinterpret_cast<uint4*>(drow) = o0;
        *reinterpret_cast<uint4*>(drow + 8) = o1;

        if (it < 2) {
            #pragma unroll
            for (int r = 0; r < 3; ++r) { mcur[r] = mnx[r]; elc[r] = eln[r]; erc[r] = ern[r]; }
            wpC = wpN; cC = cN; segC = segN;
        }
    }
    __syncthreads();

    if (tid < 384) {
        const int half = tid >= 192;
        const int r = tid - half * 192;
        const uint4* rr = reinterpret_cast<const uint4*>(
            (r < 96 ? &qs[r][0] : &ks[r - 96][0]) + half * 64);
        float s = 0.f;
        #pragma unroll
        for (int pch = 0; pch < 8; ++pch) {
            const uint4 a = rr[pch];
            s += sq2h(a.x) + sq2h(a.y) + sq2h(a.z) + sq2h(a.w);
        }
        atomicAdd(ssq + b * 192 + r, s);
    }

    {
        const int w = tid >> 6;
        const int h = w & 3, mt = w >> 2;
        const int lr2 = lane & 15, lg2 = lane >> 4;
        const int ar = h * 24 + min(mt * 16 + lr2, 23);  // clamp-dup, discard on store
        f32x4 acc2[2];
        acc2[0] = (f32x4){0.f, 0.f, 0.f, 0.f};
        acc2[1] = (f32x4){0.f, 0.f, 0.f, 0.f};
        #pragma unroll
        for (int ks4 = 0; ks4 < 4; ++ks4) {
            const f16x8 A = *(const f16x8*)(&qs[ar][ks4 * 32 + lg2 * 8]);
            #pragma unroll
            for (int nt = 0; nt < 2; ++nt) {
                const int bc = h * 24 + min(nt * 16 + lr2, 23);
                const f16x8 B = *(const f16x8*)(&ks[bc][ks4 * 32 + lg2 * 8]);
                acc2[nt] = __builtin_amdgcn_mfma_f32_16x16x32_f16(A, B, acc2[nt], 0, 0, 0);
            }
        }
        #pragma unroll
        for (int nt = 0; nt < 2; ++nt) {
            const int col = nt * 16 + lr2;
            #pragma unroll
            for (int reg = 0; reg < 4; ++reg) {
                const int row24 = mt * 16 + lg2 * 4 + reg;
                if (row24 < 24 && col < 24)
                    atomicAdd(Sg + b * 2304 + h * 576 + row24 * 24 + col, acc2[nt][reg]);
            }
        }
    }
}

// K3: normalize, softmax, fold w_out with block-diag attn -> Mf [oc][dg] f16
__global__ __launch_bounds__(256) void k_attn_fold(
    const float* __restrict__ ssq, const float* __restrict__ S,
    const float* __restrict__ temp, const float* __restrict__ w_out,
    u16* __restrict__ mf)
{
    const int b = blockIdx.x;
    const int tid = threadIdx.x;
    __shared__ float rq[96], rk[96], att[2304];

    if (tid < 96) {
        rq[tid] = 1.f / fmaxf(sqrtf(ssq[b * 192 + tid]), 1e-12f);
    } else if (tid < 192) {
        const int c = tid - 96;
        rk[c] = 1.f / fmaxf(sqrtf(ssq[b * 192 + 96 + c]), 1e-12f);
    }
    __syncthreads();

    if (tid < 96) {
        const int h = tid / 24, i = tid % 24;
        const float tmp = temp[h];
        const float rqi = rq[h * 24 + i];
        float l[24];
        float m = -1e30f;
        #pragma unroll
        for (int j = 0; j < 24; ++j) {
            l[j] = S[b * 2304 + (h * 24 + i) * 24 + j] * rqi * rk[h * 24 + j] * tmp;
            m = fmaxf(m, l[j]);
        }
        float ssum = 0.f;
        #pragma unroll
        for (int j = 0; j < 24; ++j) { l[j] = expf(l[j] - m); ssum += l[j]; }
        const float inv = 1.f / ssum;
        #pragma unroll
        for (int j = 0; j < 24; ++j) att[(h * 24 + i) * 24 + j] = l[j] * inv;
    }
    __syncthreads();

    for (int k = 0; k < 36; ++k) {
        const int id = k * 256 + tid;
        const int dg = id / 96, oc = id % 96;
        const int h = dg / 24, d24 = dg % 24;
        float s = 0.f;
        #pragma unroll
        for (int i = 0; i < 24; ++i) {
            s += w_out[oc * 96 + h * 24 + i] * att[(h * 24 + i) * 24 + d24];
        }
        mf[b * 9216 + oc * 96 + dg] = f2h(s);
    }
}

// Packed-pair 3-tap conv for one row (f16 inputs); accumulates into a[8].
__device__ __forceinline__ void row3tap(
    const uint4 m, u32 lv, u32 rv, u32 w01, u32 w2z, float* a)
{
    const u32 P0 = m.x, P1 = m.y, P2 = m.z, P3 = m.w;
    const u32 s0 = (lv >> 16) | (P0 << 16);
    const u32 s1 = (P0 >> 16) | (P1 << 16);
    const u32 s2 = (P1 >> 16) | (P2 << 16);
    const u32 s3 = (P2 >> 16) | (P3 << 16);
    const u32 s4 = (P3 >> 16) | (rv << 16);
    a[0] = fdot2a(w2z, s1, fdot2a(w01, s0, a[0]));
    a[1] = fdot2a(w2z, P1, fdot2a(w01, P0, a[1]));
    a[2] = fdot2a(w2z, s2, fdot2a(w01, s1, a[2]));
    a[3] = fdot2a(w2z, P2, fdot2a(w01, P1, a[3]));
    a[4] = fdot2a(w2z, s3, fdot2a(w01, s2, a[4]));
    a[5] = fdot2a(w2z, P3, fdot2a(w01, P2, a[5]));
    a[6] = fdot2a(w2z, s4, fdot2a(w01, s3, a[6]));
    a[7] = fdot2a(w2z, rv, fdot2a(w01, P3, a[7]));
}

// K4: fused v-dwconv + out-GEMM (f16 v planes, transposed MFMA, float4 stores).
// grid 2048, 256 thr, 32 KB.
__global__ __launch_bounds__(256, 4) void k_v_out(
    const u16* __restrict__ v16, const float* __restrict__ wkvdw,
    const u16* __restrict__ mf, float* __restrict__ out)
{
    const int bid = blockIdx.x;                  // 0..2047
    const int wg = (bid & 7) * 256 + (bid >> 3);
    const int b = wg >> 9;
    const int rem = wg & 511;
    const int y = rem >> 1;
    const int tx = (rem & 1) * 128;
    const int tid = threadIdx.x;
    const int lane = tid & 63;
    const int slot = tid >> 4;                   // 0..15 dg-pair slot
    const int chunk = tid & 15;
    const int x0l = chunk * 8;
    const int xg = tx + x0l;

    const bool vr0 = (y > 0), vr2 = (y < 255);
    const bool le = (chunk == 0) && (xg > 0);
    const bool re = (chunk == 15) && (xg + 8 < 256);

    __shared__ __align__(16) u16 xt[16384];

    auto issue = [&](int it, uint4* m0, uint4* m1, u32* e0l, u32* e0r, u32* e1l, u32* e1r) {
        const int dg = (it * 16 + slot) * 2;
        const u16* s0 = v16 + ((size_t)(b * 96 + dg)) * HWn + (y - 1) * 256 + xg;
        const u16* s1 = s0 + HWn;
        const uint4 z = make_uint4(0u, 0u, 0u, 0u);
        m0[0] = vr0 ? *reinterpret_cast<const uint4*>(s0)       : z;
        m0[1] =       *reinterpret_cast<const uint4*>(s0 + 256);
        m0[2] = vr2 ? *reinterpret_cast<const uint4*>(s0 + 512) : z;
        m1[0] = vr0 ? *reinterpret_cast<const uint4*>(s1)       : z;
        m1[1] =       *reinterpret_cast<const uint4*>(s1 + 256);
        m1[2] = vr2 ? *reinterpret_cast<const uint4*>(s1 + 512) : z;
        e0l[0] = (le && vr0) ? ((u32)s0[-1] << 16) : 0u;   e0r[0] = (re && vr0) ? (u32)s0[8] : 0u;
        e0l[1] = le ? ((u32)s0[255] << 16) : 0u;           e0r[1] = re ? (u32)s0[264] : 0u;
        e0l[2] = (le && vr2) ? ((u32)s0[511] << 16) : 0u;  e0r[2] = (re && vr2) ? (u32)s0[520] : 0u;
        e1l[0] = (le && vr0) ? ((u32)s1[-1] << 16) : 0u;   e1r[0] = (re && vr0) ? (u32)s1[8] : 0u;
        e1l[1] = le ? ((u32)s1[255] << 16) : 0u;           e1r[1] = re ? (u32)s1[264] : 0u;
        e1l[2] = (le && vr2) ? ((u32)s1[511] << 16) : 0u;  e1r[2] = (re && vr2) ? (u32)s1[520] : 0u;
    };

    uint4 m0c[3], m1c[3]; u32 e0lc[3], e0rc[3], e1lc[3], e1rc[3];
    issue(0, m0c, m1c, e0lc, e0rc, e1lc, e1rc);

    #pragma unroll 1
    for (int it = 0; it < 3; ++it) {
        uint4 m0n[3], m1n[3]; u32 e0ln[3], e0rn[3], e1ln[3], e1rn[3];
        if (it < 2) issue(it + 1, m0n, m1n, e0ln, e0rn, e1ln, e1rn);

        const int dg = (it * 16 + slot) * 2;
        const float* wp0 = wkvdw + (96 + dg) * 9;
        const float* wp1 = wp0 + 9;

        float a0[8] = {0.f, 0.f, 0.f, 0.f, 0.f, 0.f, 0.f, 0.f};
        float a1[8] = {0.f, 0.f, 0.f, 0.f, 0.f, 0.f, 0.f, 0.f};
        #pragma unroll
        for (int r = 0; r < 3; ++r) {
            {
                const u32 w01 = pack2h(wp0[r * 3 + 0], wp0[r * 3 + 1]);
                const u32 w2z = pack2h(wp0[r * 3 + 2], 0.f);
                const u32 lvn = __shfl((int)m0c[r].w, (lane - 1) & 63);
                const u32 rvn = __shfl((int)m0c[r].x, (lane + 1) & 63);
                const u32 lv = (chunk == 0)  ? e0lc[r] : lvn;
                const u32 rv = (chunk == 15) ? e0rc[r] : rvn;
                row3tap(m0c[r], lv, rv, w01, w2z, a0);
            }
            {
                const u32 w01 = pack2h(wp1[r * 3 + 0], wp1[r * 3 + 1]);
                const u32 w2z = pack2h(wp1[r * 3 + 2], 0.f);
                const u32 lvn = __shfl((int)m1c[r].w, (lane - 1) & 63);
                const u32 rvn = __shfl((int)m1c[r].x, (lane + 1) & 63);
                const u32 lv = (chunk == 0)  ? e1lc[r] : lvn;
                const u32 rv = (chunk == 15) ? e1rc[r] : rvn;
                row3tap(m1c[r], lv, rv, w01, w2z, a1);
            }
        }

        const int icb = dg >> 3, icl = dg & 7;   // even
        #pragma unroll
        for (int j = 0; j < 8; ++j) {
            *reinterpret_cast<u32*>(&xt[xoff(x0l + j, icb) + icl]) = pack2h(a0[j], a1[j]);
        }

        if (it < 2) {
            #pragma unroll
            for (int r = 0; r < 3; ++r) {
                m0c[r] = m0n[r]; m1c[r] = m1n[r];
                e0lc[r] = e0ln[r]; e0rc[r] = e0rn[r];
                e1lc[r] = e1ln[r]; e1rc[r] = e1rn[r];
            }
        }
    }
    __syncthreads();

    const u16* mh = mf + b * 9216;
    const int wv = tid >> 6;
    const int oc0 = (wv >> 1) * 48;
    const int pxw = (wv & 1) * 64;
    const int lr = lane & 15, lg = lane >> 4;

    f32x4 acc[4][3];                             // [px-frag n][oc-frag m]
    #pragma unroll
    for (int n = 0; n < 4; ++n)
        #pragma unroll
        for (int m = 0; m < 3; ++m)
            acc[n][m] = (f32x4){0.f, 0.f, 0.f, 0.f};

    #pragma unroll 1
    for (int kt = 0; kt < 3; ++kt) {
        const int kb = kt * 32;
        f16x8 XA[4];
        #pragma unroll
        for (int n = 0; n < 4; ++n)
            XA[n] = *(const f16x8*)(xt + xoff(pxw + n * 16 + lr, (kb >> 3) + lg));
        f16x8 WB[3];
        #pragma unroll
        for (int m = 0; m < 3; ++m)
            WB[m] = *(const f16x8*)(mh + (oc0 + m * 16 + lr) * 96 + kb + lg * 8);
        #pragma unroll
        for (int n = 0; n < 4; ++n)
            #pragma unroll
            for (int m = 0; m < 3; ++m)
                acc[n][m] = __builtin_amdgcn_mfma_f32_16x16x32_f16(XA[n], WB[m], acc[n][m], 0, 0, 0);
    }

    #pragma unroll
    for (int n = 0; n < 4; ++n) {
        #pragma unroll
        for (int m = 0; m < 3; ++m) {
            const int oc = oc0 + m * 16 + lr;
            float* drow = out + ((size_t)(b * 96 + oc)) * HWn + y * 256 + tx;
            const float4 o4 = make_float4(acc[n][m][0], acc[n][m][1], acc[n][m][2], acc[n][m][3]);
            *reinterpret_cast<float4*>(drow + pxw + n * 16 + lg * 4) = o4;
        }
    }
}

extern "C" void kernel_launch(void* const* d_in, const int* in_sizes, int n_in,
                              void* d_out, int out_size, void* d_ws, size_t ws_size,
                              hipStream_t stream) {
    (void)in_sizes; (void)n_in; (void)out_size; (void)ws_size;
    const float* x      = (const float*)d_in[0];
    const float* ff     = (const float*)d_in[1];
    const float* w_q    = (const float*)d_in[2];
    const float* w_kv   = (const float*)d_in[3];
    const float* w_q_dw = (const float*)d_in[4];
    const float* w_kv_dw= (const float*)d_in[5];
    const float* w_out  = (const float*)d_in[6];
    const float* temp   = (const float*)d_in[7];
    float* out = (float*)d_out;

    char* ws = (char*)d_ws;
    u8* qk8     = (u8*)(ws);                       //  50,331,648 B fp8 [b][p0..191][HW]
    u16* v16    = (u16*)(ws + 50331648);           //  50,331,648 B f16 [b][c][HW]
    float* ssq  = (float*)(ws + 100663296);        //       3,072 B
    float* S    = (float*)(ws + 100666368);        //      36,864 B
    u16* wf     = (u16*)(ws + 100703232);          //      55,296 B
    u16* mf     = (u16*)(ws + 100758528);          //      73,728 B

    hipMemsetAsync(ws + 100663296, 0, 3072 + 36864, stream);

    k_prep_w<<<108, 256, 0, stream>>>(w_q, w_kv, wf);
    k_conv_mfma<<<dim3(128, 2, 4), 256, 0, stream>>>(ff, x, wf, qk8, v16);
    k_dw_qk<<<dim3(2048), 512, 0, stream>>>(qk8, w_q_dw, w_kv_dw, ssq, S);
    k_attn_fold<<<4, 256, 0, stream>>>(ssq, S, temp, w_out, mf);
    k_v_out<<<dim3(2048), 256, 0, stream>>>(v16, w_kv_dw, mf, out);
}

// Round 20
// 249.199 us; speedup vs baseline: 1.0702x; 1.0702x over previous
//
#include <hip/hip_runtime.h>
#include <hip/hip_bf16.h>
#include <hip/hip_fp16.h>

typedef unsigned int u32;
typedef unsigned short u16;
typedef unsigned char u8;
typedef _Float16 f16;

static constexpr int HWn = 65536;

typedef __attribute__((ext_vector_type(8))) f16 f16x8;
typedef __attribute__((ext_vector_type(2))) f16 f16x2;
typedef __attribute__((ext_vector_type(4))) float f32x4;
typedef __attribute__((ext_vector_type(2))) float f32x2;

__device__ __forceinline__ float h2f(u16 u) {
    union { u16 s; f16 h; } z; z.s = u; return (float)z.h;
}
__device__ __forceinline__ u16 f2h(float f) {
    union { u16 s; f16 h; } z; z.h = (f16)f; return z.s;
}
__device__ __forceinline__ u32 pack2h(float a, float b) {
    union { u32 i; f16 h[2]; } z; z.h[0] = (f16)a; z.h[1] = (f16)b; return z.i;
}
__device__ __forceinline__ float hlo(u32 u) {
    union { u32 i; f16 h[2]; } z; z.i = u; return (float)z.h[0];
}
__device__ __forceinline__ float hhi(u32 u) {
    union { u32 i; f16 h[2]; } z; z.i = u; return (float)z.h[1];
}
__device__ __forceinline__ float sq2h(u32 a) {
    const float l = hlo(a), h = hhi(a);
    return fmaf(l, l, h * h);
}

#if defined(__has_builtin)
#if __has_builtin(__builtin_amdgcn_fdot2)
#define HAS_FDOT2 1
#endif
#endif
__device__ __forceinline__ float fdot2a(u32 a, u32 b, float c) {
#ifdef HAS_FDOT2
    union { u32 i; f16x2 h; } A, B; A.i = a; B.i = b;
    return __builtin_amdgcn_fdot2(A.h, B.h, c, false);
#else
    return fmaf(hlo(a), hlo(b), fmaf(hhi(a), hhi(b), c));
#endif
}

// Swizzled LDS offset (u16 units) for transposed X tile: [px 0..127][ic 0..95]
__device__ __forceinline__ int xoff(int px, int icb) {
    return px * 128 + (((icb ^ (px & 7) ^ ((px >> 3) & 7))) << 3);
}

// Convert conv1x1 weights to f16, layout [row 0..287][ic 0..95]
__global__ __launch_bounds__(256) void k_prep_w(
    const float* __restrict__ wq, const float* __restrict__ wkv,
    u16* __restrict__ wf)
{
    const int i = blockIdx.x * 256 + threadIdx.x;
    if (i >= 288 * 96) return;
    const int row = i / 96, ic = i % 96;
    const float w = (row < 96) ? wq[row * 96 + ic] : wkv[(row - 96) * 96 + ic];
    wf[i] = f2h(w);
}

// K1: conv1x1 via f16 MFMA, 2-subtile pipelined, transposed orientation
// (lane owns 4 consecutive px). q,k stored fp8-e4m3, v stored f16.
// Inputs loaded non-temporal (single-use; keep L3 for intermediates).
// grid (256 double-tiles, 2 sec {q, kv}, 4 b), 256 thr, 32 KB LDS.
__global__ __launch_bounds__(256, 3) void k_conv_mfma(
    const float* __restrict__ ff, const float* __restrict__ x,
    const u16* __restrict__ wf,
    u8* __restrict__ qk8, u16* __restrict__ v16)
{
    const int b = blockIdx.z, sec = blockIdx.y;
    const int pxb = blockIdx.x * 256;
    const int tid = threadIdx.x;

    __shared__ __align__(16) u16 xs[16384];     // 32 KB, f16 bits

    const float* src = (sec == 0 ? ff : x) + (size_t)b * 96 * HWn;
    const int icq = (tid >> 4) * 2;
    const int pxs = (tid & 15) * 8;
    const int lane = tid & 63;
    const int wv = tid >> 6;
    const int oc0 = (wv >> 1) * 48;
    const int pxw = (wv & 1) * 64;
    const int lr = lane & 15, lg = lane >> 4;

    f32x4 L[12];

    auto issue = [&](int x0) {
        #pragma unroll
        for (int p = 0; p < 3; ++p) {
            const float* rp0 = src + (size_t)(p * 32 + icq) * HWn + x0 + pxs;
            const float* rp1 = rp0 + HWn;
            L[p * 4 + 0] = __builtin_nontemporal_load(reinterpret_cast<const f32x4*>(rp0));
            L[p * 4 + 1] = __builtin_nontemporal_load(reinterpret_cast<const f32x4*>(rp0 + 4));
            L[p * 4 + 2] = __builtin_nontemporal_load(reinterpret_cast<const f32x4*>(rp1));
            L[p * 4 + 3] = __builtin_nontemporal_load(reinterpret_cast<const f32x4*>(rp1 + 4));
        }
    };
    auto stage = [&]() {
        #pragma unroll
        for (int p = 0; p < 3; ++p) {
            const int ic = p * 32 + icq;
            const int icb = ic >> 3, icl = ic & 7;
            const float e0[8] = {L[p*4+0][0], L[p*4+0][1], L[p*4+0][2], L[p*4+0][3],
                                 L[p*4+1][0], L[p*4+1][1], L[p*4+1][2], L[p*4+1][3]};
            const float e1[8] = {L[p*4+2][0], L[p*4+2][1], L[p*4+2][2], L[p*4+2][3],
                                 L[p*4+3][0], L[p*4+3][1], L[p*4+3][2], L[p*4+3][3]};
            #pragma unroll
            for (int j = 0; j < 8; ++j) {
                const int o = xoff(pxs + j, icb) + icl;   // even
                *reinterpret_cast<u32*>(&xs[o]) = pack2h(e0[j], e1[j]);
            }
        }
    };
    auto compute = [&](int x0) {
        const int npass = (sec == 0) ? 1 : 2;
        #pragma unroll 1
        for (int kvs = 0; kvs < npass; ++kvs) {
            const u16* wh = wf + ((sec == 0) ? 0 : (96 + kvs * 96)) * 96;
            const bool isv = (sec == 1) && (kvs == 1);
            f32x4 acc[4][3];                     // [px-frag n][oc-frag m]
            #pragma unroll
            for (int n = 0; n < 4; ++n)
                #pragma unroll
                for (int m = 0; m < 3; ++m)
                    acc[n][m] = (f32x4){0.f, 0.f, 0.f, 0.f};

            #pragma unroll 1
            for (int kt = 0; kt < 3; ++kt) {
                const int kb = kt * 32;
                f16x8 XA[4];
                #pragma unroll
                for (int n = 0; n < 4; ++n)
                    XA[n] = *(const f16x8*)(xs + xoff(pxw + n * 16 + lr, (kb >> 3) + lg));
                f16x8 WB[3];
                #pragma unroll
                for (int m = 0; m < 3; ++m)
                    WB[m] = *(const f16x8*)(wh + (oc0 + m * 16 + lr) * 96 + kb + lg * 8);
                #pragma unroll
                for (int n = 0; n < 4; ++n)
                    #pragma unroll
                    for (int m = 0; m < 3; ++m)
                        acc[n][m] = __builtin_amdgcn_mfma_f32_16x16x32_f16(XA[n], WB[m], acc[n][m], 0, 0, 0);
            }

            // lane owns px = x0 + pxw + n*16 + lg*4 (+0..3), oc = oc0 + m*16 + lr
            if (!isv) {
                u8* dst8 = qk8 + ((size_t)b * 192 + (sec == 0 ? 0 : 96)) * (size_t)HWn;
                #pragma unroll
                for (int n = 0; n < 4; ++n) {
                    #pragma unroll
                    for (int m = 0; m < 3; ++m) {
                        const int oc = oc0 + m * 16 + lr;
                        u32 pk = (u32)__builtin_amdgcn_cvt_pk_fp8_f32(acc[n][m][0], acc[n][m][1], 0, false);
                        pk = (u32)__builtin_amdgcn_cvt_pk_fp8_f32(acc[n][m][2], acc[n][m][3], (int)pk, true);
                        *reinterpret_cast<u32*>(dst8 + (size_t)oc * HWn + x0 + pxw + n * 16 + lg * 4) = pk;
                    }
                }
            } else {
                u16* dstv = v16 + (size_t)b * 96 * HWn;
                #pragma unroll
                for (int n = 0; n < 4; ++n) {
                    #pragma unroll
                    for (int m = 0; m < 3; ++m) {
                        const int oc = oc0 + m * 16 + lr;
                        ushort4 sv;
                        sv.x = f2h(acc[n][m][0]); sv.y = f2h(acc[n][m][1]);
                        sv.z = f2h(acc[n][m][2]); sv.w = f2h(acc[n][m][3]);
                        *reinterpret_cast<ushort4*>(dstv + (size_t)oc * HWn + x0 + pxw + n * 16 + lg * 4) = sv;
                    }
                }
            }
        }
    };

    issue(pxb);
    stage();
    __syncthreads();
    issue(pxb + 128);        // second subtile loads in flight during compute
    compute(pxb);
    __syncthreads();
    stage();
    __syncthreads();
    compute(pxb + 128);
}

// Packed-pair 3-tap conv for one row (f16 inputs); accumulates into a[8].
__device__ __forceinline__ void row3tap(
    const uint4 m, u32 lv, u32 rv, u32 w01, u32 w2z, float* a)
{
    const u32 P0 = m.x, P1 = m.y, P2 = m.z, P3 = m.w;
    const u32 s0 = (lv >> 16) | (P0 << 16);
    const u32 s1 = (P0 >> 16) | (P1 << 16);
    const u32 s2 = (P1 >> 16) | (P2 << 16);
    const u32 s3 = (P2 >> 16) | (P3 << 16);
    const u32 s4 = (P3 >> 16) | (rv << 16);
    a[0] = fdot2a(w2z, s1, fdot2a(w01, s0, a[0]));
    a[1] = fdot2a(w2z, P1, fdot2a(w01, P0, a[1]));
    a[2] = fdot2a(w2z, s2, fdot2a(w01, s1, a[2]));
    a[3] = fdot2a(w2z, P2, fdot2a(w01, P1, a[3]));
    a[4] = fdot2a(w2z, s3, fdot2a(w01, s2, a[4]));
    a[5] = fdot2a(w2z, P3, fdot2a(w01, P2, a[5]));
    a[6] = fdot2a(w2z, s4, fdot2a(w01, s3, a[6]));
    a[7] = fdot2a(w2z, rv, fdot2a(w01, P3, a[7]));
}

// K2: depthwise 3x3 for q,k (fp8 planes 0..191) + ssq + S via MFMA.
// 128-px half-row tiles, 512 thr, 52 KB LDS, 1-deep prefetch. (R15 version.)
__global__ __launch_bounds__(512) void k_dw_qk(
    const u8* __restrict__ qk8,
    const float* __restrict__ wqdw, const float* __restrict__ wkvdw,
    float* __restrict__ ssq, float* __restrict__ Sg)
{
    const int bid = blockIdx.x;                  // 0..2047
    const int wg = (bid & 7) * 256 + (bid >> 3); // XCD: contiguous y span per XCD
    const int b = wg >> 9;
    const int rem = wg & 511;
    const int y = rem >> 1;
    const int tx = (rem & 1) * 128;
    const int tid = threadIdx.x;
    const int lane = tid & 63;
    const int pq = tid >> 4;                     // 0..31 plane-within-iter
    const int chunk = tid & 15;
    const int x0l = chunk * 8;
    const int xg = tx + x0l;

    const bool vr0 = (y > 0), vr2 = (y < 255);
    const bool le = (chunk == 0) && (xg > 0);
    const bool re = (chunk == 15) && (xg + 8 < 256);

    __shared__ __align__(16) u16 qs[96][136];
    __shared__ __align__(16) u16 ks[96][136];

    auto addr = [&](int it, const u8*& r0, const float*& wp, int& c, int& seg) {
        const int p = it * 32 + pq;              // 0..191 == plane index
        r0 = qk8 + ((size_t)(b * 192 + p)) * HWn + (y - 1) * 256 + xg;
        if (p < 96) { c = p;      wp = wqdw  + p * 9;        seg = 0; }
        else        { c = p - 96; wp = wkvdw + (p - 96) * 9; seg = 1; }
    };
    // edge bytes staged so left sits at byte3, right at byte0 (const cvt sel)
    auto issue = [&](const u8* r0, uint2* m, u32* el, u32* er) {
        const uint2 z = make_uint2(0u, 0u);
        const u8* r1 = r0 + 256;
        const u8* r2 = r1 + 256;
        m[0] = vr0 ? *reinterpret_cast<const uint2*>(r0) : z;
        m[1] = *reinterpret_cast<const uint2*>(r1);
        m[2] = vr2 ? *reinterpret_cast<const uint2*>(r2) : z;
        el[0] = (le && vr0) ? ((u32)r0[-1] << 24) : 0u;  er[0] = (re && vr0) ? (u32)r0[8] : 0u;
        el[1] = le ? ((u32)r1[-1] << 24) : 0u;           er[1] = re ? (u32)r1[8] : 0u;
        el[2] = (le && vr2) ? ((u32)r2[-1] << 24) : 0u;  er[2] = (re && vr2) ? (u32)r2[8] : 0u;
    };

    const u8* srcC; const float* wpC; int cC, segC;
    addr(0, srcC, wpC, cC, segC);
    uint2 mcur[3]; u32 elc[3], erc[3];
    issue(srcC, mcur, elc, erc);

    #pragma unroll 1
    for (int it = 0; it < 6; ++it) {
        const u8* srcN; const float* wpN; int cN, segN;
        uint2 mnx[3]; u32 eln[3], ern[3];
        if (it < 5) {
            addr(it + 1, srcN, wpN, cN, segN);
            issue(srcN, mnx, eln, ern);
        }

        float a[8] = {0.f, 0.f, 0.f, 0.f, 0.f, 0.f, 0.f, 0.f};
        #pragma unroll
        for (int r = 0; r < 3; ++r) {
            const uint2 u = mcur[r];
            const f32x2 p01 = __builtin_amdgcn_cvt_pk_f32_fp8((int)u.x, false);
            const f32x2 p23 = __builtin_amdgcn_cvt_pk_f32_fp8((int)u.x, true);
            const f32x2 p45 = __builtin_amdgcn_cvt_pk_f32_fp8((int)u.y, false);
            const f32x2 p67 = __builtin_amdgcn_cvt_pk_f32_fp8((int)u.y, true);
            const u32 ln = (u32)__shfl((int)u.y, (lane - 1) & 63);
            const u32 rn = (u32)__shfl((int)u.x, (lane + 1) & 63);
            const u32 lsel = (chunk == 0)  ? elc[r] : ln;   // want byte3
            const u32 rsel = (chunk == 15) ? erc[r] : rn;   // want byte0
            const f32x2 lcv = __builtin_amdgcn_cvt_pk_f32_fp8((int)lsel, true);
            const f32x2 rcv = __builtin_amdgcn_cvt_pk_f32_fp8((int)rsel, false);
            const float v[10] = {
                lcv[1],
                p01[0], p01[1], p23[0], p23[1], p45[0], p45[1], p67[0], p67[1],
                rcv[0]
            };
            const float w0 = wpC[r * 3 + 0], w1 = wpC[r * 3 + 1], w2 = wpC[r * 3 + 2];
            #pragma unroll
            for (int j = 0; j < 8; ++j)
                a[j] = fmaf(w0, v[j], fmaf(w1, v[j + 1], fmaf(w2, v[j + 2], a[j])));
        }

        const uint4 o = make_uint4(pack2h(a[0], a[1]), pack2h(a[2], a[3]),
                                   pack2h(a[4], a[5]), pack2h(a[6], a[7]));
        if (segC == 0) *reinterpret_cast<uint4*>(&qs[cC][x0l]) = o;
        else           *reinterpret_cast<uint4*>(&ks[cC][x0l]) = o;

        if (it < 5) {
            #pragma unroll
            for (int r = 0; r < 3; ++r) { mcur[r] = mnx[r]; elc[r] = eln[r]; erc[r] = ern[r]; }
            wpC = wpN; cC = cN; segC = segN;
        }
    }
    __syncthreads();

    if (tid < 384) {
        const int half = tid >= 192;
        const int r = tid - half * 192;
        const uint4* rr = reinterpret_cast<const uint4*>(
            (r < 96 ? &qs[r][0] : &ks[r - 96][0]) + half * 64);
        float s = 0.f;
        #pragma unroll
        for (int pch = 0; pch < 8; ++pch) {
            const uint4 a = rr[pch];
            s += sq2h(a.x) + sq2h(a.y) + sq2h(a.z) + sq2h(a.w);
        }
        atomicAdd(ssq + b * 192 + r, s);
    }

    {
        const int w = tid >> 6;
        const int h = w & 3, mt = w >> 2;
        const int lr2 = lane & 15, lg2 = lane >> 4;
        const int ar = h * 24 + min(mt * 16 + lr2, 23);  // clamp-dup, discard on store
        f32x4 acc2[2];
        acc2[0] = (f32x4){0.f, 0.f, 0.f, 0.f};
        acc2[1] = (f32x4){0.f, 0.f, 0.f, 0.f};
        #pragma unroll
        for (int ks4 = 0; ks4 < 4; ++ks4) {
            const f16x8 A = *(const f16x8*)(&qs[ar][ks4 * 32 + lg2 * 8]);
            #pragma unroll
            for (int nt = 0; nt < 2; ++nt) {
                const int bc = h * 24 + min(nt * 16 + lr2, 23);
                const f16x8 B = *(const f16x8*)(&ks[bc][ks4 * 32 + lg2 * 8]);
                acc2[nt] = __builtin_amdgcn_mfma_f32_16x16x32_f16(A, B, acc2[nt], 0, 0, 0);
            }
        }
        #pragma unroll
        for (int nt = 0; nt < 2; ++nt) {
            const int col = nt * 16 + lr2;
            #pragma unroll
            for (int reg = 0; reg < 4; ++reg) {
                const int row24 = mt * 16 + lg2 * 4 + reg;
                if (row24 < 24 && col < 24)
                    atomicAdd(Sg + b * 2304 + h * 576 + row24 * 24 + col, acc2[nt][reg]);
            }
        }
    }
}

// K3: normalize, softmax, fold w_out with block-diag attn -> Mf [oc][dg] f16
__global__ __launch_bounds__(256) void k_attn_fold(
    const float* __restrict__ ssq, const float* __restrict__ S,
    const float* __restrict__ temp, const float* __restrict__ w_out,
    u16* __restrict__ mf)
{
    const int b = blockIdx.x;
    const int tid = threadIdx.x;
    __shared__ float rq[96], rk[96], att[2304];

    if (tid < 96) {
        rq[tid] = 1.f / fmaxf(sqrtf(ssq[b * 192 + tid]), 1e-12f);
    } else if (tid < 192) {
        const int c = tid - 96;
        rk[c] = 1.f / fmaxf(sqrtf(ssq[b * 192 + 96 + c]), 1e-12f);
    }
    __syncthreads();

    if (tid < 96) {
        const int h = tid / 24, i = tid % 24;
        const float tmp = temp[h];
        const float rqi = rq[h * 24 + i];
        float l[24];
        float m = -1e30f;
        #pragma unroll
        for (int j = 0; j < 24; ++j) {
            l[j] = S[b * 2304 + (h * 24 + i) * 24 + j] * rqi * rk[h * 24 + j] * tmp;
            m = fmaxf(m, l[j]);
        }
        float ssum = 0.f;
        #pragma unroll
        for (int j = 0; j < 24; ++j) { l[j] = expf(l[j] - m); ssum += l[j]; }
        const float inv = 1.f / ssum;
        #pragma unroll
        for (int j = 0; j < 24; ++j) att[(h * 24 + i) * 24 + j] = l[j] * inv;
    }
    __syncthreads();

    for (int k = 0; k < 36; ++k) {
        const int id = k * 256 + tid;
        const int dg = id / 96, oc = id % 96;
        const int h = dg / 24, d24 = dg % 24;
        float s = 0.f;
        #pragma unroll
        for (int i = 0; i < 24; ++i) {
            s += w_out[oc * 96 + h * 24 + i] * att[(h * 24 + i) * 24 + d24];
        }
        mf[b * 9216 + oc * 96 + dg] = f2h(s);
    }
}

// K4: fused v-dwconv + out-GEMM (f16 v planes, transposed MFMA, f32x4
// non-temporal out stores). grid 2048, 256 thr, 32 KB.
__global__ __launch_bounds__(256, 4) void k_v_out(
    const u16* __restrict__ v16, const float* __restrict__ wkvdw,
    const u16* __restrict__ mf, float* __restrict__ out)
{
    const int bid = blockIdx.x;                  // 0..2047
    const int wg = (bid & 7) * 256 + (bid >> 3);
    const int b = wg >> 9;
    const int rem = wg & 511;
    const int y = rem >> 1;
    const int tx = (rem & 1) * 128;
    const int tid = threadIdx.x;
    const int lane = tid & 63;
    const int slot = tid >> 4;                   // 0..15 dg-pair slot
    const int chunk = tid & 15;
    const int x0l = chunk * 8;
    const int xg = tx + x0l;

    const bool vr0 = (y > 0), vr2 = (y < 255);
    const bool le = (chunk == 0) && (xg > 0);
    const bool re = (chunk == 15) && (xg + 8 < 256);

    __shared__ __align__(16) u16 xt[16384];

    auto issue = [&](int it, uint4* m0, uint4* m1, u32* e0l, u32* e0r, u32* e1l, u32* e1r) {
        const int dg = (it * 16 + slot) * 2;
        const u16* s0 = v16 + ((size_t)(b * 96 + dg)) * HWn + (y - 1) * 256 + xg;
        const u16* s1 = s0 + HWn;
        const uint4 z = make_uint4(0u, 0u, 0u, 0u);
        m0[0] = vr0 ? *reinterpret_cast<const uint4*>(s0)       : z;
        m0[1] =       *reinterpret_cast<const uint4*>(s0 + 256);
        m0[2] = vr2 ? *reinterpret_cast<const uint4*>(s0 + 512) : z;
        m1[0] = vr0 ? *reinterpret_cast<const uint4*>(s1)       : z;
        m1[1] =       *reinterpret_cast<const uint4*>(s1 + 256);
        m1[2] = vr2 ? *reinterpret_cast<const uint4*>(s1 + 512) : z;
        e0l[0] = (le && vr0) ? ((u32)s0[-1] << 16) : 0u;   e0r[0] = (re && vr0) ? (u32)s0[8] : 0u;
        e0l[1] = le ? ((u32)s0[255] << 16) : 0u;           e0r[1] = re ? (u32)s0[264] : 0u;
        e0l[2] = (le && vr2) ? ((u32)s0[511] << 16) : 0u;  e0r[2] = (re && vr2) ? (u32)s0[520] : 0u;
        e1l[0] = (le && vr0) ? ((u32)s1[-1] << 16) : 0u;   e1r[0] = (re && vr0) ? (u32)s1[8] : 0u;
        e1l[1] = le ? ((u32)s1[255] << 16) : 0u;           e1r[1] = re ? (u32)s1[264] : 0u;
        e1l[2] = (le && vr2) ? ((u32)s1[511] << 16) : 0u;  e1r[2] = (re && vr2) ? (u32)s1[520] : 0u;
    };

    uint4 m0c[3], m1c[3]; u32 e0lc[3], e0rc[3], e1lc[3], e1rc[3];
    issue(0, m0c, m1c, e0lc, e0rc, e1lc, e1rc);

    #pragma unroll 1
    for (int it = 0; it < 3; ++it) {
        uint4 m0n[3], m1n[3]; u32 e0ln[3], e0rn[3], e1ln[3], e1rn[3];
        if (it < 2) issue(it + 1, m0n, m1n, e0ln, e0rn, e1ln, e1rn);

        const int dg = (it * 16 + slot) * 2;
        const float* wp0 = wkvdw + (96 + dg) * 9;
        const float* wp1 = wp0 + 9;

        float a0[8] = {0.f, 0.f, 0.f, 0.f, 0.f, 0.f, 0.f, 0.f};
        float a1[8] = {0.f, 0.f, 0.f, 0.f, 0.f, 0.f, 0.f, 0.f};
        #pragma unroll
        for (int r = 0; r < 3; ++r) {
            {
                const u32 w01 = pack2h(wp0[r * 3 + 0], wp0[r * 3 + 1]);
                const u32 w2z = pack2h(wp0[r * 3 + 2], 0.f);
                const u32 lvn = __shfl((int)m0c[r].w, (lane - 1) & 63);
                const u32 rvn = __shfl((int)m0c[r].x, (lane + 1) & 63);
                const u32 lv = (chunk == 0)  ? e0lc[r] : lvn;
                const u32 rv = (chunk == 15) ? e0rc[r] : rvn;
                row3tap(m0c[r], lv, rv, w01, w2z, a0);
            }
            {
                const u32 w01 = pack2h(wp1[r * 3 + 0], wp1[r * 3 + 1]);
                const u32 w2z = pack2h(wp1[r * 3 + 2], 0.f);
                const u32 lvn = __shfl((int)m1c[r].w, (lane - 1) & 63);
                const u32 rvn = __shfl((int)m1c[r].x, (lane + 1) & 63);
                const u32 lv = (chunk == 0)  ? e1lc[r] : lvn;
                const u32 rv = (chunk == 15) ? e1rc[r] : rvn;
                row3tap(m1c[r], lv, rv, w01, w2z, a1);
            }
        }

        const int icb = dg >> 3, icl = dg & 7;   // even
        #pragma unroll
        for (int j = 0; j < 8; ++j) {
            *reinterpret_cast<u32*>(&xt[xoff(x0l + j, icb) + icl]) = pack2h(a0[j], a1[j]);
        }

        if (it < 2) {
            #pragma unroll
            for (int r = 0; r < 3; ++r) {
                m0c[r] = m0n[r]; m1c[r] = m1n[r];
                e0lc[r] = e0ln[r]; e0rc[r] = e0rn[r];
                e1lc[r] = e1ln[r]; e1rc[r] = e1rn[r];
            }
        }
    }
    __syncthreads();

    const u16* mh = mf + b * 9216;
    const int wv = tid >> 6;
    const int oc0 = (wv >> 1) * 48;
    const int pxw = (wv & 1) * 64;
    const int lr = lane & 15, lg = lane >> 4;

    f32x4 acc[4][3];                             // [px-frag n][oc-frag m]
    #pragma unroll
    for (int n = 0; n < 4; ++n)
        #pragma unroll
        for (int m = 0; m < 3; ++m)
            acc[n][m] = (f32x4){0.f, 0.f, 0.f, 0.f};

    #pragma unroll 1
    for (int kt = 0; kt < 3; ++kt) {
        const int kb = kt * 32;
        f16x8 XA[4];
        #pragma unroll
        for (int n = 0; n < 4; ++n)
            XA[n] = *(const f16x8*)(xt + xoff(pxw + n * 16 + lr, (kb >> 3) + lg));
        f16x8 WB[3];
        #pragma unroll
        for (int m = 0; m < 3; ++m)
            WB[m] = *(const f16x8*)(mh + (oc0 + m * 16 + lr) * 96 + kb + lg * 8);
        #pragma unroll
        for (int n = 0; n < 4; ++n)
            #pragma unroll
            for (int m = 0; m < 3; ++m)
                acc[n][m] = __builtin_amdgcn_mfma_f32_16x16x32_f16(XA[n], WB[m], acc[n][m], 0, 0, 0);
    }

    #pragma unroll
    for (int n = 0; n < 4; ++n) {
        #pragma unroll
        for (int m = 0; m < 3; ++m) {
            const int oc = oc0 + m * 16 + lr;
            float* drow = out + ((size_t)(b * 96 + oc)) * HWn + y * 256 + tx;
            __builtin_nontemporal_store(acc[n][m], reinterpret_cast<f32x4*>(drow + pxw + n * 16 + lg * 4));
        }
    }
}

extern "C" void kernel_launch(void* const* d_in, const int* in_sizes, int n_in,
                              void* d_out, int out_size, void* d_ws, size_t ws_size,
                              hipStream_t stream) {
    (void)in_sizes; (void)n_in; (void)out_size; (void)ws_size;
    const float* x      = (const float*)d_in[0];
    const float* ff     = (const float*)d_in[1];
    const float* w_q    = (const float*)d_in[2];
    const float* w_kv   = (const float*)d_in[3];
    const float* w_q_dw = (const float*)d_in[4];
    const float* w_kv_dw= (const float*)d_in[5];
    const float* w_out  = (const float*)d_in[6];
    const float* temp   = (const float*)d_in[7];
    float* out = (float*)d_out;

    char* ws = (char*)d_ws;
    u8* qk8     = (u8*)(ws);                       //  50,331,648 B fp8 [b][p0..191][HW]
    u16* v16    = (u16*)(ws + 50331648);           //  50,331,648 B f16 [b][c][HW]
    float* ssq  = (float*)(ws + 100663296);        //       3,072 B
    float* S    = (float*)(ws + 100666368);        //      36,864 B
    u16* wf     = (u16*)(ws + 100703232);          //      55,296 B
    u16* mf     = (u16*)(ws + 100758528);          //      73,728 B

    hipMemsetAsync(ws + 100663296, 0, 3072 + 36864, stream);

    k_prep_w<<<108, 256, 0, stream>>>(w_q, w_kv, wf);
    k_conv_mfma<<<dim3(256, 2, 4), 256, 0, stream>>>(ff, x, wf, qk8, v16);
    k_dw_qk<<<dim3(2048), 512, 0, stream>>>(qk8, w_q_dw, w_kv_dw, ssq, S);
    k_attn_fold<<<4, 256, 0, stream>>>(ssq, S, temp, w_out, mf);
    k_v_out<<<dim3(2048), 256, 0, stream>>>(v16, w_kv_dw, mf, out);
}

// Round 21
// 248.157 us; speedup vs baseline: 1.0747x; 1.0042x over previous
//
#include <hip/hip_runtime.h>
#include <hip/hip_bf16.h>
#include <hip/hip_fp16.h>

typedef unsigned int u32;
typedef unsigned short u16;
typedef unsigned char u8;
typedef _Float16 f16;

static constexpr int HWn = 65536;

typedef __attribute__((ext_vector_type(8))) f16 f16x8;
typedef __attribute__((ext_vector_type(2))) f16 f16x2;
typedef __attribute__((ext_vector_type(4))) float f32x4;
typedef __attribute__((ext_vector_type(2))) float f32x2;

__device__ __forceinline__ float h2f(u16 u) {
    union { u16 s; f16 h; } z; z.s = u; return (float)z.h;
}
__device__ __forceinline__ u16 f2h(float f) {
    union { u16 s; f16 h; } z; z.h = (f16)f; return z.s;
}
__device__ __forceinline__ u32 pack2h(float a, float b) {
    union { u32 i; f16 h[2]; } z; z.h[0] = (f16)a; z.h[1] = (f16)b; return z.i;
}
__device__ __forceinline__ float hlo(u32 u) {
    union { u32 i; f16 h[2]; } z; z.i = u; return (float)z.h[0];
}
__device__ __forceinline__ float hhi(u32 u) {
    union { u32 i; f16 h[2]; } z; z.i = u; return (float)z.h[1];
}
__device__ __forceinline__ float sq2h(u32 a) {
    const float l = hlo(a), h = hhi(a);
    return fmaf(l, l, h * h);
}

#if defined(__has_builtin)
#if __has_builtin(__builtin_amdgcn_fdot2)
#define HAS_FDOT2 1
#endif
#endif
__device__ __forceinline__ float fdot2a(u32 a, u32 b, float c) {
#ifdef HAS_FDOT2
    union { u32 i; f16x2 h; } A, B; A.i = a; B.i = b;
    return __builtin_amdgcn_fdot2(A.h, B.h, c, false);
#else
    return fmaf(hlo(a), hlo(b), fmaf(hhi(a), hhi(b), c));
#endif
}

// Swizzled LDS offset (u16 units) for transposed X tile: [px 0..127][ic 0..95]
__device__ __forceinline__ int xoff(int px, int icb) {
    return px * 128 + (((icb ^ (px & 7) ^ ((px >> 3) & 7))) << 3);
}

// Convert conv1x1 weights to f16, layout [row 0..287][ic 0..95]
__global__ __launch_bounds__(256) void k_prep_w(
    const float* __restrict__ wq, const float* __restrict__ wkv,
    u16* __restrict__ wf)
{
    const int i = blockIdx.x * 256 + threadIdx.x;
    if (i >= 288 * 96) return;
    const int row = i / 96, ic = i % 96;
    const float w = (row < 96) ? wq[row * 96 + ic] : wkv[(row - 96) * 96 + ic];
    wf[i] = f2h(w);
}

// K1: conv1x1 via f16 MFMA, 2-subtile pipelined, transposed orientation
// (lane owns 4 consecutive px). q,k stored fp8-e4m3, v stored f16.
// Inputs loaded non-temporal (single-use; keep L3 for intermediates).
// grid (256 double-tiles, 2 sec {q, kv}, 4 b), 256 thr, 32 KB LDS.
__global__ __launch_bounds__(256, 3) void k_conv_mfma(
    const float* __restrict__ ff, const float* __restrict__ x,
    const u16* __restrict__ wf,
    u8* __restrict__ qk8, u16* __restrict__ v16)
{
    const int b = blockIdx.z, sec = blockIdx.y;
    const int pxb = blockIdx.x * 256;
    const int tid = threadIdx.x;

    __shared__ __align__(16) u16 xs[16384];     // 32 KB, f16 bits

    const float* src = (sec == 0 ? ff : x) + (size_t)b * 96 * HWn;
    const int icq = (tid >> 4) * 2;
    const int pxs = (tid & 15) * 8;
    const int lane = tid & 63;
    const int wv = tid >> 6;
    const int oc0 = (wv >> 1) * 48;
    const int pxw = (wv & 1) * 64;
    const int lr = lane & 15, lg = lane >> 4;

    f32x4 L[12];

    auto issue = [&](int x0) {
        #pragma unroll
        for (int p = 0; p < 3; ++p) {
            const float* rp0 = src + (size_t)(p * 32 + icq) * HWn + x0 + pxs;
            const float* rp1 = rp0 + HWn;
            L[p * 4 + 0] = __builtin_nontemporal_load(reinterpret_cast<const f32x4*>(rp0));
            L[p * 4 + 1] = __builtin_nontemporal_load(reinterpret_cast<const f32x4*>(rp0 + 4));
            L[p * 4 + 2] = __builtin_nontemporal_load(reinterpret_cast<const f32x4*>(rp1));
            L[p * 4 + 3] = __builtin_nontemporal_load(reinterpret_cast<const f32x4*>(rp1 + 4));
        }
    };
    auto stage = [&]() {
        #pragma unroll
        for (int p = 0; p < 3; ++p) {
            const int ic = p * 32 + icq;
            const int icb = ic >> 3, icl = ic & 7;
            const float e0[8] = {L[p*4+0][0], L[p*4+0][1], L[p*4+0][2], L[p*4+0][3],
                                 L[p*4+1][0], L[p*4+1][1], L[p*4+1][2], L[p*4+1][3]};
            const float e1[8] = {L[p*4+2][0], L[p*4+2][1], L[p*4+2][2], L[p*4+2][3],
                                 L[p*4+3][0], L[p*4+3][1], L[p*4+3][2], L[p*4+3][3]};
            #pragma unroll
            for (int j = 0; j < 8; ++j) {
                const int o = xoff(pxs + j, icb) + icl;   // even
                *reinterpret_cast<u32*>(&xs[o]) = pack2h(e0[j], e1[j]);
            }
        }
    };
    auto compute = [&](int x0) {
        const int npass = (sec == 0) ? 1 : 2;
        #pragma unroll 1
        for (int kvs = 0; kvs < npass; ++kvs) {
            const u16* wh = wf + ((sec == 0) ? 0 : (96 + kvs * 96)) * 96;
            const bool isv = (sec == 1) && (kvs == 1);
            f32x4 acc[4][3];                     // [px-frag n][oc-frag m]
            #pragma unroll
            for (int n = 0; n < 4; ++n)
                #pragma unroll
                for (int m = 0; m < 3; ++m)
                    acc[n][m] = (f32x4){0.f, 0.f, 0.f, 0.f};

            #pragma unroll 1
            for (int kt = 0; kt < 3; ++kt) {
                const int kb = kt * 32;
                f16x8 XA[4];
                #pragma unroll
                for (int n = 0; n < 4; ++n)
                    XA[n] = *(const f16x8*)(xs + xoff(pxw + n * 16 + lr, (kb >> 3) + lg));
                f16x8 WB[3];
                #pragma unroll
                for (int m = 0; m < 3; ++m)
                    WB[m] = *(const f16x8*)(wh + (oc0 + m * 16 + lr) * 96 + kb + lg * 8);
                #pragma unroll
                for (int n = 0; n < 4; ++n)
                    #pragma unroll
                    for (int m = 0; m < 3; ++m)
                        acc[n][m] = __builtin_amdgcn_mfma_f32_16x16x32_f16(XA[n], WB[m], acc[n][m], 0, 0, 0);
            }

            // lane owns px = x0 + pxw + n*16 + lg*4 (+0..3), oc = oc0 + m*16 + lr
            if (!isv) {
                u8* dst8 = qk8 + ((size_t)b * 192 + (sec == 0 ? 0 : 96)) * (size_t)HWn;
                #pragma unroll
                for (int n = 0; n < 4; ++n) {
                    #pragma unroll
                    for (int m = 0; m < 3; ++m) {
                        const int oc = oc0 + m * 16 + lr;
                        u32 pk = (u32)__builtin_amdgcn_cvt_pk_fp8_f32(acc[n][m][0], acc[n][m][1], 0, false);
                        pk = (u32)__builtin_amdgcn_cvt_pk_fp8_f32(acc[n][m][2], acc[n][m][3], (int)pk, true);
                        *reinterpret_cast<u32*>(dst8 + (size_t)oc * HWn + x0 + pxw + n * 16 + lg * 4) = pk;
                    }
                }
            } else {
                u16* dstv = v16 + (size_t)b * 96 * HWn;
                #pragma unroll
                for (int n = 0; n < 4; ++n) {
                    #pragma unroll
                    for (int m = 0; m < 3; ++m) {
                        const int oc = oc0 + m * 16 + lr;
                        ushort4 sv;
                        sv.x = f2h(acc[n][m][0]); sv.y = f2h(acc[n][m][1]);
                        sv.z = f2h(acc[n][m][2]); sv.w = f2h(acc[n][m][3]);
                        *reinterpret_cast<ushort4*>(dstv + (size_t)oc * HWn + x0 + pxw + n * 16 + lg * 4) = sv;
                    }
                }
            }
        }
    };

    issue(pxb);
    stage();
    __syncthreads();
    issue(pxb + 128);        // second subtile loads in flight during compute
    compute(pxb);
    __syncthreads();
    stage();
    __syncthreads();
    compute(pxb + 128);
}

// Packed-pair 3-tap conv for one row (f16 inputs); accumulates into a[8].
__device__ __forceinline__ void row3tap(
    const uint4 m, u32 lv, u32 rv, u32 w01, u32 w2z, float* a)
{
    const u32 P0 = m.x, P1 = m.y, P2 = m.z, P3 = m.w;
    const u32 s0 = (lv >> 16) | (P0 << 16);
    const u32 s1 = (P0 >> 16) | (P1 << 16);
    const u32 s2 = (P1 >> 16) | (P2 << 16);
    const u32 s3 = (P2 >> 16) | (P3 << 16);
    const u32 s4 = (P3 >> 16) | (rv << 16);
    a[0] = fdot2a(w2z, s1, fdot2a(w01, s0, a[0]));
    a[1] = fdot2a(w2z, P1, fdot2a(w01, P0, a[1]));
    a[2] = fdot2a(w2z, s2, fdot2a(w01, s1, a[2]));
    a[3] = fdot2a(w2z, P2, fdot2a(w01, P1, a[3]));
    a[4] = fdot2a(w2z, s3, fdot2a(w01, s2, a[4]));
    a[5] = fdot2a(w2z, P3, fdot2a(w01, P2, a[5]));
    a[6] = fdot2a(w2z, s4, fdot2a(w01, s3, a[6]));
    a[7] = fdot2a(w2z, rv, fdot2a(w01, P3, a[7]));
}

// K2: depthwise 3x3 for q,k (fp8 planes 0..191) + ssq + S via MFMA.
// 128-px half-row tiles, 512 thr, 52 KB LDS, 1-deep prefetch. (R15 version.)
__global__ __launch_bounds__(512) void k_dw_qk(
    const u8* __restrict__ qk8,
    const float* __restrict__ wqdw, const float* __restrict__ wkvdw,
    float* __restrict__ ssq, float* __restrict__ Sg)
{
    const int bid = blockIdx.x;                  // 0..2047
    const int wg = (bid & 7) * 256 + (bid >> 3); // XCD: contiguous y span per XCD
    const int b = wg >> 9;
    const int rem = wg & 511;
    const int y = rem >> 1;
    const int tx = (rem & 1) * 128;
    const int tid = threadIdx.x;
    const int lane = tid & 63;
    const int pq = tid >> 4;                     // 0..31 plane-within-iter
    const int chunk = tid & 15;
    const int x0l = chunk * 8;
    const int xg = tx + x0l;

    const bool vr0 = (y > 0), vr2 = (y < 255);
    const bool le = (chunk == 0) && (xg > 0);
    const bool re = (chunk == 15) && (xg + 8 < 256);

    __shared__ __align__(16) u16 qs[96][136];
    __shared__ __align__(16) u16 ks[96][136];

    auto addr = [&](int it, const u8*& r0, const float*& wp, int& c, int& seg) {
        const int p = it * 32 + pq;              // 0..191 == plane index
        r0 = qk8 + ((size_t)(b * 192 + p)) * HWn + (y - 1) * 256 + xg;
        if (p < 96) { c = p;      wp = wqdw  + p * 9;        seg = 0; }
        else        { c = p - 96; wp = wkvdw + (p - 96) * 9; seg = 1; }
    };
    // edge bytes staged so left sits at byte3, right at byte0 (const cvt sel)
    auto issue = [&](const u8* r0, uint2* m, u32* el, u32* er) {
        const uint2 z = make_uint2(0u, 0u);
        const u8* r1 = r0 + 256;
        const u8* r2 = r1 + 256;
        m[0] = vr0 ? *reinterpret_cast<const uint2*>(r0) : z;
        m[1] = *reinterpret_cast<const uint2*>(r1);
        m[2] = vr2 ? *reinterpret_cast<const uint2*>(r2) : z;
        el[0] = (le && vr0) ? ((u32)r0[-1] << 24) : 0u;  er[0] = (re && vr0) ? (u32)r0[8] : 0u;
        el[1] = le ? ((u32)r1[-1] << 24) : 0u;           er[1] = re ? (u32)r1[8] : 0u;
        el[2] = (le && vr2) ? ((u32)r2[-1] << 24) : 0u;  er[2] = (re && vr2) ? (u32)r2[8] : 0u;
    };

    const u8* srcC; const float* wpC; int cC, segC;
    addr(0, srcC, wpC, cC, segC);
    uint2 mcur[3]; u32 elc[3], erc[3];
    issue(srcC, mcur, elc, erc);

    #pragma unroll 1
    for (int it = 0; it < 6; ++it) {
        const u8* srcN; const float* wpN; int cN, segN;
        uint2 mnx[3]; u32 eln[3], ern[3];
        if (it < 5) {
            addr(it + 1, srcN, wpN, cN, segN);
            issue(srcN, mnx, eln, ern);
        }

        float a[8] = {0.f, 0.f, 0.f, 0.f, 0.f, 0.f, 0.f, 0.f};
        #pragma unroll
        for (int r = 0; r < 3; ++r) {
            const uint2 u = mcur[r];
            const f32x2 p01 = __builtin_amdgcn_cvt_pk_f32_fp8((int)u.x, false);
            const f32x2 p23 = __builtin_amdgcn_cvt_pk_f32_fp8((int)u.x, true);
            const f32x2 p45 = __builtin_amdgcn_cvt_pk_f32_fp8((int)u.y, false);
            const f32x2 p67 = __builtin_amdgcn_cvt_pk_f32_fp8((int)u.y, true);
            const u32 ln = (u32)__shfl((int)u.y, (lane - 1) & 63);
            const u32 rn = (u32)__shfl((int)u.x, (lane + 1) & 63);
            const u32 lsel = (chunk == 0)  ? elc[r] : ln;   // want byte3
            const u32 rsel = (chunk == 15) ? erc[r] : rn;   // want byte0
            const f32x2 lcv = __builtin_amdgcn_cvt_pk_f32_fp8((int)lsel, true);
            const f32x2 rcv = __builtin_amdgcn_cvt_pk_f32_fp8((int)rsel, false);
            const float v[10] = {
                lcv[1],
                p01[0], p01[1], p23[0], p23[1], p45[0], p45[1], p67[0], p67[1],
                rcv[0]
            };
            const float w0 = wpC[r * 3 + 0], w1 = wpC[r * 3 + 1], w2 = wpC[r * 3 + 2];
            #pragma unroll
            for (int j = 0; j < 8; ++j)
                a[j] = fmaf(w0, v[j], fmaf(w1, v[j + 1], fmaf(w2, v[j + 2], a[j])));
        }

        const uint4 o = make_uint4(pack2h(a[0], a[1]), pack2h(a[2], a[3]),
                                   pack2h(a[4], a[5]), pack2h(a[6], a[7]));
        if (segC == 0) *reinterpret_cast<uint4*>(&qs[cC][x0l]) = o;
        else           *reinterpret_cast<uint4*>(&ks[cC][x0l]) = o;

        if (it < 5) {
            #pragma unroll
            for (int r = 0; r < 3; ++r) { mcur[r] = mnx[r]; elc[r] = eln[r]; erc[r] = ern[r]; }
            wpC = wpN; cC = cN; segC = segN;
        }
    }
    __syncthreads();

    if (tid < 384) {
        const int half = tid >= 192;
        const int r = tid - half * 192;
        const uint4* rr = reinterpret_cast<const uint4*>(
            (r < 96 ? &qs[r][0] : &ks[r - 96][0]) + half * 64);
        float s = 0.f;
        #pragma unroll
        for (int pch = 0; pch < 8; ++pch) {
            const uint4 a = rr[pch];
            s += sq2h(a.x) + sq2h(a.y) + sq2h(a.z) + sq2h(a.w);
        }
        atomicAdd(ssq + b * 192 + r, s);
    }

    {
        const int w = tid >> 6;
        const int h = w & 3, mt = w >> 2;
        const int lr2 = lane & 15, lg2 = lane >> 4;
        const int ar = h * 24 + min(mt * 16 + lr2, 23);  // clamp-dup, discard on store
        f32x4 acc2[2];
        acc2[0] = (f32x4){0.f, 0.f, 0.f, 0.f};
        acc2[1] = (f32x4){0.f, 0.f, 0.f, 0.f};
        #pragma unroll
        for (int ks4 = 0; ks4 < 4; ++ks4) {
            const f16x8 A = *(const f16x8*)(&qs[ar][ks4 * 32 + lg2 * 8]);
            #pragma unroll
            for (int nt = 0; nt < 2; ++nt) {
                const int bc = h * 24 + min(nt * 16 + lr2, 23);
                const f16x8 B = *(const f16x8*)(&ks[bc][ks4 * 32 + lg2 * 8]);
                acc2[nt] = __builtin_amdgcn_mfma_f32_16x16x32_f16(A, B, acc2[nt], 0, 0, 0);
            }
        }
        #pragma unroll
        for (int nt = 0; nt < 2; ++nt) {
            const int col = nt * 16 + lr2;
            #pragma unroll
            for (int reg = 0; reg < 4; ++reg) {
                const int row24 = mt * 16 + lg2 * 4 + reg;
                if (row24 < 24 && col < 24)
                    atomicAdd(Sg + b * 2304 + h * 576 + row24 * 24 + col, acc2[nt][reg]);
            }
        }
    }
}

// K3: normalize, softmax, fold w_out with block-diag attn -> Mf [oc][dg] f16
__global__ __launch_bounds__(256) void k_attn_fold(
    const float* __restrict__ ssq, const float* __restrict__ S,
    const float* __restrict__ temp, const float* __restrict__ w_out,
    u16* __restrict__ mf)
{
    const int b = blockIdx.x;
    const int tid = threadIdx.x;
    __shared__ float rq[96], rk[96], att[2304];

    if (tid < 96) {
        rq[tid] = 1.f / fmaxf(sqrtf(ssq[b * 192 + tid]), 1e-12f);
    } else if (tid < 192) {
        const int c = tid - 96;
        rk[c] = 1.f / fmaxf(sqrtf(ssq[b * 192 + 96 + c]), 1e-12f);
    }
    __syncthreads();

    if (tid < 96) {
        const int h = tid / 24, i = tid % 24;
        const float tmp = temp[h];
        const float rqi = rq[h * 24 + i];
        float l[24];
        float m = -1e30f;
        #pragma unroll
        for (int j = 0; j < 24; ++j) {
            l[j] = S[b * 2304 + (h * 24 + i) * 24 + j] * rqi * rk[h * 24 + j] * tmp;
            m = fmaxf(m, l[j]);
        }
        float ssum = 0.f;
        #pragma unroll
        for (int j = 0; j < 24; ++j) { l[j] = expf(l[j] - m); ssum += l[j]; }
        const float inv = 1.f / ssum;
        #pragma unroll
        for (int j = 0; j < 24; ++j) att[(h * 24 + i) * 24 + j] = l[j] * inv;
    }
    __syncthreads();

    for (int k = 0; k < 36; ++k) {
        const int id = k * 256 + tid;
        const int dg = id / 96, oc = id % 96;
        const int h = dg / 24, d24 = dg % 24;
        float s = 0.f;
        #pragma unroll
        for (int i = 0; i < 24; ++i) {
            s += w_out[oc * 96 + h * 24 + i] * att[(h * 24 + i) * 24 + d24];
        }
        mf[b * 9216 + oc * 96 + dg] = f2h(s);
    }
}

// K4: fused v-dwconv + out-GEMM (f16 v planes, transposed MFMA, regular f32x4
// out stores). grid 2048, 256 thr, 32 KB.
__global__ __launch_bounds__(256, 4) void k_v_out(
    const u16* __restrict__ v16, const float* __restrict__ wkvdw,
    const u16* __restrict__ mf, float* __restrict__ out)
{
    const int bid = blockIdx.x;                  // 0..2047
    const int wg = (bid & 7) * 256 + (bid >> 3);
    const int b = wg >> 9;
    const int rem = wg & 511;
    const int y = rem >> 1;
    const int tx = (rem & 1) * 128;
    const int tid = threadIdx.x;
    const int lane = tid & 63;
    const int slot = tid >> 4;                   // 0..15 dg-pair slot
    const int chunk = tid & 15;
    const int x0l = chunk * 8;
    const int xg = tx + x0l;

    const bool vr0 = (y > 0), vr2 = (y < 255);
    const bool le = (chunk == 0) && (xg > 0);
    const bool re = (chunk == 15) && (xg + 8 < 256);

    __shared__ __align__(16) u16 xt[16384];

    auto issue = [&](int it, uint4* m0, uint4* m1, u32* e0l, u32* e0r, u32* e1l, u32* e1r) {
        const int dg = (it * 16 + slot) * 2;
        const u16* s0 = v16 + ((size_t)(b * 96 + dg)) * HWn + (y - 1) * 256 + xg;
        const u16* s1 = s0 + HWn;
        const uint4 z = make_uint4(0u, 0u, 0u, 0u);
        m0[0] = vr0 ? *reinterpret_cast<const uint4*>(s0)       : z;
        m0[1] =       *reinterpret_cast<const uint4*>(s0 + 256);
        m0[2] = vr2 ? *reinterpret_cast<const uint4*>(s0 + 512) : z;
        m1[0] = vr0 ? *reinterpret_cast<const uint4*>(s1)       : z;
        m1[1] =       *reinterpret_cast<const uint4*>(s1 + 256);
        m1[2] = vr2 ? *reinterpret_cast<const uint4*>(s1 + 512) : z;
        e0l[0] = (le && vr0) ? ((u32)s0[-1] << 16) : 0u;   e0r[0] = (re && vr0) ? (u32)s0[8] : 0u;
        e0l[1] = le ? ((u32)s0[255] << 16) : 0u;           e0r[1] = re ? (u32)s0[264] : 0u;
        e0l[2] = (le && vr2) ? ((u32)s0[511] << 16) : 0u;  e0r[2] = (re && vr2) ? (u32)s0[520] : 0u;
        e1l[0] = (le && vr0) ? ((u32)s1[-1] << 16) : 0u;   e1r[0] = (re && vr0) ? (u32)s1[8] : 0u;
        e1l[1] = le ? ((u32)s1[255] << 16) : 0u;           e1r[1] = re ? (u32)s1[264] : 0u;
        e1l[2] = (le && vr2) ? ((u32)s1[511] << 16) : 0u;  e1r[2] = (re && vr2) ? (u32)s1[520] : 0u;
    };

    uint4 m0c[3], m1c[3]; u32 e0lc[3], e0rc[3], e1lc[3], e1rc[3];
    issue(0, m0c, m1c, e0lc, e0rc, e1lc, e1rc);

    #pragma unroll 1
    for (int it = 0; it < 3; ++it) {
        uint4 m0n[3], m1n[3]; u32 e0ln[3], e0rn[3], e1ln[3], e1rn[3];
        if (it < 2) issue(it + 1, m0n, m1n, e0ln, e0rn, e1ln, e1rn);

        const int dg = (it * 16 + slot) * 2;
        const float* wp0 = wkvdw + (96 + dg) * 9;
        const float* wp1 = wp0 + 9;

        float a0[8] = {0.f, 0.f, 0.f, 0.f, 0.f, 0.f, 0.f, 0.f};
        float a1[8] = {0.f, 0.f, 0.f, 0.f, 0.f, 0.f, 0.f, 0.f};
        #pragma unroll
        for (int r = 0; r < 3; ++r) {
            {
                const u32 w01 = pack2h(wp0[r * 3 + 0], wp0[r * 3 + 1]);
                const u32 w2z = pack2h(wp0[r * 3 + 2], 0.f);
                const u32 lvn = __shfl((int)m0c[r].w, (lane - 1) & 63);
                const u32 rvn = __shfl((int)m0c[r].x, (lane + 1) & 63);
                const u32 lv = (chunk == 0)  ? e0lc[r] : lvn;
                const u32 rv = (chunk == 15) ? e0rc[r] : rvn;
                row3tap(m0c[r], lv, rv, w01, w2z, a0);
            }
            {
                const u32 w01 = pack2h(wp1[r * 3 + 0], wp1[r * 3 + 1]);
                const u32 w2z = pack2h(wp1[r * 3 + 2], 0.f);
                const u32 lvn = __shfl((int)m1c[r].w, (lane - 1) & 63);
                const u32 rvn = __shfl((int)m1c[r].x, (lane + 1) & 63);
                const u32 lv = (chunk == 0)  ? e1lc[r] : lvn;
                const u32 rv = (chunk == 15) ? e1rc[r] : rvn;
                row3tap(m1c[r], lv, rv, w01, w2z, a1);
            }
        }

        const int icb = dg >> 3, icl = dg & 7;   // even
        #pragma unroll
        for (int j = 0; j < 8; ++j) {
            *reinterpret_cast<u32*>(&xt[xoff(x0l + j, icb) + icl]) = pack2h(a0[j], a1[j]);
        }

        if (it < 2) {
            #pragma unroll
            for (int r = 0; r < 3; ++r) {
                m0c[r] = m0n[r]; m1c[r] = m1n[r];
                e0lc[r] = e0ln[r]; e0rc[r] = e0rn[r];
                e1lc[r] = e1ln[r]; e1rc[r] = e1rn[r];
            }
        }
    }
    __syncthreads();

    const u16* mh = mf + b * 9216;
    const int wv = tid >> 6;
    const int oc0 = (wv >> 1) * 48;
    const int pxw = (wv & 1) * 64;
    const int lr = lane & 15, lg = lane >> 4;

    f32x4 acc[4][3];                             // [px-frag n][oc-frag m]
    #pragma unroll
    for (int n = 0; n < 4; ++n)
        #pragma unroll
        for (int m = 0; m < 3; ++m)
            acc[n][m] = (f32x4){0.f, 0.f, 0.f, 0.f};

    #pragma unroll 1
    for (int kt = 0; kt < 3; ++kt) {
        const int kb = kt * 32;
        f16x8 XA[4];
        #pragma unroll
        for (int n = 0; n < 4; ++n)
            XA[n] = *(const f16x8*)(xt + xoff(pxw + n * 16 + lr, (kb >> 3) + lg));
        f16x8 WB[3];
        #pragma unroll
        for (int m = 0; m < 3; ++m)
            WB[m] = *(const f16x8*)(mh + (oc0 + m * 16 + lr) * 96 + kb + lg * 8);
        #pragma unroll
        for (int n = 0; n < 4; ++n)
            #pragma unroll
            for (int m = 0; m < 3; ++m)
                acc[n][m] = __builtin_amdgcn_mfma_f32_16x16x32_f16(XA[n], WB[m], acc[n][m], 0, 0, 0);
    }

    #pragma unroll
    for (int n = 0; n < 4; ++n) {
        #pragma unroll
        for (int m = 0; m < 3; ++m) {
            const int oc = oc0 + m * 16 + lr;
            float* drow = out + ((size_t)(b * 96 + oc)) * HWn + y * 256 + tx;
            *reinterpret_cast<f32x4*>(drow + pxw + n * 16 + lg * 4) = acc[n][m];
        }
    }
}

extern "C" void kernel_launch(void* const* d_in, const int* in_sizes, int n_in,
                              void* d_out, int out_size, void* d_ws, size_t ws_size,
                              hipStream_t stream) {
    (void)in_sizes; (void)n_in; (void)out_size; (void)ws_size;
    const float* x      = (const float*)d_in[0];
    const float* ff     = (const float*)d_in[1];
    const float* w_q    = (const float*)d_in[2];
    const float* w_kv   = (const float*)d_in[3];
    const float* w_q_dw = (const float*)d_in[4];
    const float* w_kv_dw= (const float*)d_in[5];
    const float* w_out  = (const float*)d_in[6];
    const float* temp   = (const float*)d_in[7];
    float* out = (float*)d_out;

    char* ws = (char*)d_ws;
    u8* qk8     = (u8*)(ws);                       //  50,331,648 B fp8 [b][p0..191][HW]
    u16* v16    = (u16*)(ws + 50331648);           //  50,331,648 B f16 [b][c][HW]
    float* ssq  = (float*)(ws + 100663296);        //       3,072 B
    float* S    = (float*)(ws + 100666368);        //      36,864 B
    u16* wf     = (u16*)(ws + 100703232);          //      55,296 B
    u16* mf     = (u16*)(ws + 100758528);          //      73,728 B

    hipMemsetAsync(ws + 100663296, 0, 3072 + 36864, stream);

    k_prep_w<<<108, 256, 0, stream>>>(w_q, w_kv, wf);
    k_conv_mfma<<<dim3(256, 2, 4), 256, 0, stream>>>(ff, x, wf, qk8, v16);
    k_dw_qk<<<dim3(2048), 512, 0, stream>>>(qk8, w_q_dw, w_kv_dw, ssq, S);
    k_attn_fold<<<4, 256, 0, stream>>>(ssq, S, temp, w_out, mf);
    k_v_out<<<dim3(2048), 256, 0, stream>>>(v16, w_kv_dw, mf, out);
}